// Round 6
// baseline (932.836 us; speedup 1.0000x reference)
//
#include <hip/hip_runtime.h>

// 2-layer LSTM (PyTorch gate order i,f,g,o), L=2048, B=512, INPUT=78, H=4.
//
// R11: fused producer-consumer; producer weights DISTRIBUTED across lanes.
//   R9/R10 post-mortem: compiler refuses to keep a 78-float weight row
//   register-resident per lane (VGPR_Count 68/64 < 78 both rounds) -> every
//   pass re-read weights, passes serialized at ~4.6k cycles. Fix: split the
//   dot-78 over 4 lanes. Producer lane = a*4+q: a = output j*4+g (16), q =
//   k-quarter. Each lane holds 10 prescaled float2 weights (20 VGPRs --
//   trivially resident), computes a partial dot over k in [20q,20q+20)
//   (q==3 masked to 18), butterfly-reduce over q via ds_swizzle ^1,^2, the
//   q==0 lanes store one coalesced 64B line per (t,b) row. Wave w pass p
//   covers t = 4p+(w-1), both batches. ~60 instr/pass, passes independent
//   -> ~50us per producer wave, hidden under the consumer's 260us.
//   Watermark: signal every 4 passes -> granularity 16 t; avail = 16*min.
//
//   256 blocks x 320 threads (1 block/CU): wave 0 = R6-verified consumer
//   recurrence (16 lanes/(batch,layer), one gate/lane, 4 trans ops/step,
//   quad_perm gate gather, 7 ds_swizzle XORs, prefetch 8, measured 260us),
//   gated on block-local LDS watermarks. Handoff same-CU only; consumer
//   first-touches an xg line strictly after its producer store (gate), so
//   no stale-L1 exposure (empirically clean in R9/R10, passed).
//
// ws: [20480 B, 20480+64MiB) xg0[t][b][j*4+g], prescaled by +-log2e.

#define LSEQ  2048
#define BATCH 512
#define NIN   78
#define LOG2E 1.4426950408889634f

#define WS_XG_F    5120
#define XG_BYTES   ((unsigned)LSEQ * BATCH * 16u * 4u)

typedef __attribute__((ext_vector_type(2))) float vf2;

__device__ __forceinline__ float rcp_(float x) { return __builtin_amdgcn_rcpf(x); }
__device__ __forceinline__ float ex2_(float x) { return __builtin_amdgcn_exp2f(x); }
__device__ __forceinline__ vf2 pkfma(vf2 a, vf2 b, vf2 c) {
  return __builtin_elementwise_fma(a, b, c);
}

template<int CTRL>
__device__ __forceinline__ float dppf(float x) {
  int r = __builtin_amdgcn_update_dpp(0, __builtin_bit_cast(int, x), CTRL, 0xf, 0xf, false);
  return __builtin_bit_cast(float, r);
}
template<int PAT>
__device__ __forceinline__ float swzf(float x) {
  int r = __builtin_amdgcn_ds_swizzle(__builtin_bit_cast(int, x), PAT);
  return __builtin_bit_cast(float, r);
}

__global__ __launch_bounds__(320) void lstm_fused(
    const float* __restrict__ x,
    const int* __restrict__ lens,
    const float* __restrict__ Wih0, const float* __restrict__ Whh0,
    const float* __restrict__ bih0, const float* __restrict__ bhh0,
    const float* __restrict__ Wih1, const float* __restrict__ Whh1,
    const float* __restrict__ bih1, const float* __restrict__ bhh1,
    float* __restrict__ ws, float* __restrict__ out)
{
  __shared__ unsigned long long progq;   // 4 x u16 producer watermarks
  const int tid  = threadIdx.x;
  const int wave = tid >> 6;
  const int lane = tid & 63;
  if (tid == 0) progq = 0ull;
  __syncthreads();                       // only barrier in the kernel
  const int b0 = blockIdx.x * 2;

  if (wave != 0) {
    // ------------- producers (waves 1..4), distributed weights -----------
    const int w = wave;                  // 1..4
    const int q = lane & 3;              // k-quarter
    const int a = (lane >> 2) & 15;      // output index j*4+g
    const int j = a >> 2, g = a & 3;
    const float s = (g == 2) ? 2.f * LOG2E : -LOG2E;
    const int row = g * 4 + j;           // PyTorch row = gate*4 + unit

    // 10 prescaled float2 weights for k in [20q, 20q+20); q==3 has 18 (mask)
    vf2 wq[10];
    {
      const float* wrow = Wih0 + row * NIN + q * 20;
#pragma unroll
      for (int i = 0; i < 9; ++i)
        wq[i] = vf2{ s * wrow[2 * i], s * wrow[2 * i + 1] };
      wq[9] = vf2{ 0.f, 0.f };
      if (q < 3) wq[9] = vf2{ s * wrow[18], s * wrow[19] };
    }
    const float bias0 = s * (bih0[row] + bhh0[row]);

    float* __restrict__ xg = ws + WS_XG_F;
    volatile unsigned short* pr = (volatile unsigned short*)&progq;

    for (int p = 0; p < LSEQ / 4; ++p) {
      const int t = 4 * p + (w - 1);
      const float* xr0 = x + ((size_t)t * BATCH + b0) * NIN + q * 20;
      const float* xr1 = xr0 + NIN;      // next batch, same t
      vf2 acc0 = vf2{ 0.f, 0.f }, acc1 = vf2{ 0.f, 0.f };
#pragma unroll
      for (int i = 0; i < 9; ++i) {
        acc0 = pkfma(*(const vf2*)(xr0 + 2 * i), wq[i], acc0);
        acc1 = pkfma(*(const vf2*)(xr1 + 2 * i), wq[i], acc1);
      }
      if (q < 3) {                       // masked tail (avoids OOB reads)
        acc0 = pkfma(*(const vf2*)(xr0 + 18), wq[9], acc0);
        acc1 = pkfma(*(const vf2*)(xr1 + 18), wq[9], acc1);
      }
      float s0 = acc0.x + acc0.y;
      float s1 = acc1.x + acc1.y;
      // butterfly over q (lane ^1, ^2): all 4 q-lanes end with the full dot
      s0 += swzf<0x041F>(s0); s0 += swzf<0x081F>(s0);
      s1 += swzf<0x041F>(s1); s1 += swzf<0x081F>(s1);
      s0 += bias0; s1 += bias0;
      if (q == 0) {                      // 16 lanes -> one 64B line per row
        xg[((size_t)t * BATCH + b0) * 16 + a] = s0;
        xg[((size_t)t * BATCH + b0 + 1) * 16 + a] = s1;
      }
      if ((p & 3) == 3) {                // fence+signal every 4 passes (16 t)
        __threadfence_block();
        if (lane == 0) pr[w - 1] = (unsigned short)((p >> 2) + 1);
      }
    }
    return;
  }

  // ---------------- consumer (wave 0): R6 recurrence (verified) ----------
  const int g     = lane & 3;            // gate: 0=i 1=f 2=g 3=o
  const int j     = (lane >> 2) & 3;     // hidden unit
  const int layer = (lane >> 4) & 1;
  const int b     = b0 + (lane >> 5);

  const float sg = (g == 2) ? 2.f * LOG2E : -LOG2E;
  const float ka = (g == 2) ? -4.f * LOG2E : 1.f;
  const float kb = (g == 2) ?  2.f * LOG2E : 0.f;

  const int row4 = (g * 4 + j) * 4;
  const float* whh = layer ? Whh1 : Whh0;
  float wA[4], wB[4];
#pragma unroll
  for (int m = 0; m < 4; ++m) {          // A_m = h[j^m] (ds_swizzle xor map)
    wA[m] = sg * whh[row4 + (j ^ m)];
    wB[m] = layer ? sg * Wih1[row4 + (j ^ m)] : 0.f;
  }
  const int len = lens[b];

  // base = keep*buf + badd: layer0 takes streamed xg (bias folded in),
  // layer1 takes its constant prescaled bias.
  const float keep = layer ? 0.f : 1.f;
  const float badd = layer ? sg * (bih1[g * 4 + j] + bhh1[g * 4 + j]) : 0.f;

  unsigned ofs = layer ? (unsigned)(WS_XG_F * 4)
                       : (unsigned)(WS_XG_F * 4 + (b * 16 + j * 4 + g) * 4);
  const unsigned stride = layer ? 0u : (unsigned)(BATCH * 16 * 4);
  const unsigned maxofs = (unsigned)(WS_XG_F * 4) + XG_BYTES - 4u;

  float* sp = out + b * 4 + j;           // stored by (layer==1, g==0) lanes

  float A0 = 0.f, A1 = 0.f, A2 = 0.f, A3 = 0.f;
  float B0 = 0.f, B1 = 0.f, B2 = 0.f, B3 = 0.f;
  float cs = 0.f;

  const char* wsr = (const char*)ws;
  auto ld1 = [&](unsigned o) -> float {
    o = (o > maxofs) ? maxofs : o;
    return *(const float*)(wsr + o);
  };

  volatile unsigned long long* pq = &progq;
  int avail = 0;
  auto wait_t = [&](int need) {          // ensure t < need all produced
    if (avail >= need) return;
    for (;;) {
      const unsigned long long v = *pq;  // ds_read_b64, wave-uniform
      unsigned v0 = (unsigned)(v & 0xffff);
      unsigned v1 = (unsigned)((v >> 16) & 0xffff);
      unsigned v2 = (unsigned)((v >> 32) & 0xffff);
      unsigned v3 = (unsigned)((v >> 48) & 0xffff);
      unsigned m01 = v0 < v1 ? v0 : v1;
      unsigned m23 = v2 < v3 ? v2 : v3;
      unsigned mn  = m01 < m23 ? m01 : m23;
      avail = (int)(16u * mn);           // 16-t watermark granularity
      if (avail >= need) break;
      __builtin_amdgcn_s_sleep(8);
    }
    asm volatile("" ::: "memory");       // no hoisting loads above the gate
  };

  auto step = [&](const float bufv, int t, bool do_store) {
    const float base = fmaf(keep, bufv, badd);
    float p0 = fmaf(A0, wA[0], base);
    p0 = fmaf(A1, wA[1], p0);
    float p1 = A2 * wA[2];
    p1 = fmaf(A3, wA[3], p1);
    float p2 = fmaf(B0, wB[0], B1 * wB[1]);
    float p3 = fmaf(B2, wB[2], B3 * wB[3]);
    const float P = (p0 + p1) + (p2 + p3);

    const float r   = rcp_(1.f + ex2_(P));
    const float act = fmaf(ka, r, kb);

    const float vi = dppf<0x00>(act), vf = dppf<0x55>(act),
                vg = dppf<0xAA>(act), vo = dppf<0xFF>(act);

    cs = fmaf(vf, cs, vi * vg);
    const float tc = fmaf(-2.f, rcp_(1.f + ex2_(cs)), 1.f);
    const float hq = vo * tc;

    A0 = hq;
    A1 = swzf<0x101F>(hq);               // lane ^ 4
    A2 = swzf<0x201F>(hq);               // lane ^ 8
    A3 = swzf<0x301F>(hq);               // lane ^ 12
    B0 = swzf<0x401F>(hq);               // lane ^ 16 (layer ship)
    B1 = swzf<0x501F>(hq);               // lane ^ 20
    B2 = swzf<0x601F>(hq);               // lane ^ 24
    B3 = swzf<0x701F>(hq);               // lane ^ 28

    if (do_store) {
      if (layer && g == 0) *sp = (t < len) ? hq : 0.f;
      sp += BATCH * 4;
    }
  };

  // prologue: prefetch t=0..7 (gated), step t=0, reset layer1, load t=8
  wait_t(16);
  float buf[8];
#pragma unroll
  for (int p = 0; p < 8; ++p) { buf[p] = ld1(ofs); ofs += stride; }
  step(buf[0], -1, false);
  if (layer) { cs = 0.f; A0 = 0.f; A1 = 0.f; A2 = 0.f; A3 = 0.f; }
  buf[0] = ld1(ofs); ofs += stride;

  // main: window wi covers k = 8wi+1..8wi+8; loads fetch t = 8wi+9..8wi+16
  // -> gate on avail >= 8wi+24, cap LSEQ.
  for (int wi = 0; wi < LSEQ / 8; ++wi) {
    int need = 8 * wi + 24;
    if (need > LSEQ) need = LSEQ;
    wait_t(need);
#pragma unroll
    for (int kk = 0; kk < 8; ++kk) {
      const int k = 8 * wi + 1 + kk;
      step(buf[(1 + kk) & 7], k - 1, true);
      buf[(1 + kk) & 7] = ld1(ofs); ofs += stride;
    }
  }
}

extern "C" void kernel_launch(void* const* d_in, const int* in_sizes, int n_in,
                              void* d_out, int out_size, void* d_ws, size_t ws_size,
                              hipStream_t stream) {
  const float* x    = (const float*)d_in[0];
  const int*   lens = (const int*)d_in[1];
  const float* Wih0 = (const float*)d_in[2];
  const float* Whh0 = (const float*)d_in[3];
  const float* bih0 = (const float*)d_in[4];
  const float* bhh0 = (const float*)d_in[5];
  const float* Wih1 = (const float*)d_in[6];
  const float* Whh1 = (const float*)d_in[7];
  const float* bih1 = (const float*)d_in[8];
  const float* bhh1 = (const float*)d_in[9];
  float* ws  = (float*)d_ws;
  float* out = (float*)d_out;

  lstm_fused<<<BATCH / 2, 320, 0, stream>>>(
      x, lens, Wih0, Whh0, bih0, bhh0, Wih1, Whh1, bih1, bhh1, ws, out);
}